// Round 1
// baseline (1499.063 us; speedup 1.0000x reference)
//
#include <hip/hip_runtime.h>

#define D 128
#define OUT_D 128
#define ROWS_PER_BLOCK 8

// Kernel 1: edge-parallel gather + scatter-add.
// One thread handles one (edge, 4-float chunk): 32 threads per edge.
__global__ void edge_scatter_kernel(const float* __restrict__ x_src,
                                    const int* __restrict__ edge_src,
                                    const int* __restrict__ edge_dst,
                                    float* __restrict__ summed,
                                    float* __restrict__ count,
                                    long long total_chunks) {
    long long tid = (long long)blockIdx.x * blockDim.x + threadIdx.x;
    if (tid >= total_chunks) return;
    int e = (int)(tid >> 5);
    int c = (int)(tid & 31);          // which float4 chunk of the 128-wide row
    int s = edge_src[e];
    int d = edge_dst[e];
    const float4 v = *reinterpret_cast<const float4*>(x_src + (long long)s * D + c * 4);
    float* dst = summed + (long long)d * D + c * 4;
    atomicAdd(dst + 0, v.x);
    atomicAdd(dst + 1, v.y);
    atomicAdd(dst + 2, v.z);
    atomicAdd(dst + 3, v.w);
    if (c == 0) atomicAdd(count + d, 1.0f);
}

// Kernel 2: agg = summed / max(count,1); out = agg @ Wn + x_dst @ Ws + (bn+bs)
// 128 threads/block (one per output column), 8 dst rows per block.
// Row data staged in LDS (broadcast reads across k, conflict-free);
// W reads are coalesced across threads and amortized 8x across rows.
__global__ void out_kernel(const float* __restrict__ summed,
                           const float* __restrict__ count,
                           const float* __restrict__ x_dst,
                           const float* __restrict__ Wn,   // [D][OUT]
                           const float* __restrict__ bn,
                           const float* __restrict__ Ws,   // [D][OUT]
                           const float* __restrict__ bs,
                           float* __restrict__ out,
                           int N) {
    __shared__ float aggL[ROWS_PER_BLOCK][D];
    __shared__ float xdL[ROWS_PER_BLOCK][D];
    const int n = threadIdx.x;             // output column 0..127
    const int row0 = blockIdx.x * ROWS_PER_BLOCK;

    #pragma unroll
    for (int r = 0; r < ROWS_PER_BLOCK; ++r) {
        int row = row0 + r;
        float a = 0.f, xv = 0.f;
        if (row < N) {
            float cnt = count[row];
            float inv = 1.0f / fmaxf(cnt, 1.0f);
            a  = summed[(long long)row * D + n] * inv;
            xv = x_dst[(long long)row * D + n];
        }
        aggL[r][n] = a;
        xdL[r][n]  = xv;
    }
    __syncthreads();

    const float b = bn[n] + bs[n];
    float acc[ROWS_PER_BLOCK];
    #pragma unroll
    for (int r = 0; r < ROWS_PER_BLOCK; ++r) acc[r] = b;

    for (int k = 0; k < D; ++k) {
        float wn = Wn[k * OUT_D + n];
        float ws = Ws[k * OUT_D + n];
        #pragma unroll
        for (int r = 0; r < ROWS_PER_BLOCK; ++r) {
            acc[r] = fmaf(aggL[r][k], wn, fmaf(xdL[r][k], ws, acc[r]));
        }
    }

    #pragma unroll
    for (int r = 0; r < ROWS_PER_BLOCK; ++r) {
        int row = row0 + r;
        if (row < N) out[(long long)row * OUT_D + n] = acc[r];
    }
}

extern "C" void kernel_launch(void* const* d_in, const int* in_sizes, int n_in,
                              void* d_out, int out_size, void* d_ws, size_t ws_size,
                              hipStream_t stream) {
    const float* x_src    = (const float*)d_in[0];
    const float* x_dst    = (const float*)d_in[1];
    const int*   edge_src = (const int*)d_in[2];
    const int*   edge_dst = (const int*)d_in[3];
    // d_in[4] = num_dst scalar (device); derive N from x_dst size instead.
    const float* Wn = (const float*)d_in[5];
    const float* bn = (const float*)d_in[6];
    const float* Ws = (const float*)d_in[7];
    const float* bs = (const float*)d_in[8];

    const int E = in_sizes[2];
    const int N = in_sizes[1] / D;   // num_dst

    float* summed = (float*)d_ws;
    float* count  = summed + (size_t)N * D;

    size_t zero_bytes = ((size_t)N * D + (size_t)N) * sizeof(float);
    hipMemsetAsync(d_ws, 0, zero_bytes, stream);

    long long total_chunks = (long long)E * 32;
    int threads = 256;
    long long blocks = (total_chunks + threads - 1) / threads;
    edge_scatter_kernel<<<(dim3)(unsigned)blocks, threads, 0, stream>>>(
        x_src, edge_src, edge_dst, summed, count, total_chunks);

    int oblocks = (N + ROWS_PER_BLOCK - 1) / ROWS_PER_BLOCK;
    out_kernel<<<oblocks, OUT_D, 0, stream>>>(
        summed, count, x_dst, Wn, bn, Ws, bs, (float*)d_out, N);
}

// Round 2
// 388.750 us; speedup vs baseline: 3.8561x; 3.8561x over previous
//
#include <hip/hip_runtime.h>

#define D 128
#define OUT_D 128
#define ROWS_PER_BLOCK 8
#define SCAN_THREADS 1024

// --- CSR build stage ---------------------------------------------------

__global__ void hist_kernel(const int* __restrict__ edge_dst,
                            int* __restrict__ counts, int E) {
    int e = blockIdx.x * blockDim.x + threadIdx.x;
    if (e < E) atomicAdd(&counts[edge_dst[e]], 1);
}

// Single-block exclusive scan over N counts -> offsets[N+1]; also primes cursor.
__global__ void scan_kernel(const int* __restrict__ counts,
                            int* __restrict__ offsets,
                            int* __restrict__ cursor, int N, int E) {
    __shared__ int sums[SCAN_THREADS];
    const int t = threadIdx.x;
    const int chunk = (N + SCAN_THREADS - 1) / SCAN_THREADS;
    const int lo = t * chunk;
    const int hi = min(lo + chunk, N);
    int s = 0;
    for (int i = lo; i < hi; ++i) s += counts[i];
    sums[t] = s;
    __syncthreads();
    // Hillis-Steele inclusive scan
    for (int ofs = 1; ofs < SCAN_THREADS; ofs <<= 1) {
        int v = (t >= ofs) ? sums[t - ofs] : 0;
        __syncthreads();
        sums[t] += v;
        __syncthreads();
    }
    int run = (t == 0) ? 0 : sums[t - 1];
    for (int i = lo; i < hi; ++i) {
        offsets[i] = run;
        cursor[i]  = run;
        run += counts[i];
    }
    if (t == SCAN_THREADS - 1) offsets[N] = E;
}

__global__ void fill_kernel(const int* __restrict__ edge_src,
                            const int* __restrict__ edge_dst,
                            int* __restrict__ cursor,
                            int* __restrict__ eidx, int E) {
    int e = blockIdx.x * blockDim.x + threadIdx.x;
    if (e < E) {
        int pos = atomicAdd(&cursor[edge_dst[e]], 1);
        eidx[pos] = edge_src[e];
    }
}

// --- Aggregation: one wave per dst row, register accumulation ----------

__global__ void gather_kernel(const float* __restrict__ x_src,
                              const int* __restrict__ offsets,
                              const int* __restrict__ eidx,
                              float* __restrict__ agg, int N) {
    const int wave = (int)((blockIdx.x * (long long)blockDim.x + threadIdx.x) >> 6);
    const int lane = threadIdx.x & 63;
    if (wave >= N) return;
    const int beg = offsets[wave];
    const int end = offsets[wave + 1];
    float2 acc = make_float2(0.f, 0.f);
    for (int i = beg; i < end; ++i) {
        int s = eidx[i];  // wave-uniform load
        const float2 v = *reinterpret_cast<const float2*>(
            x_src + (size_t)s * D + lane * 2);
        acc.x += v.x;
        acc.y += v.y;
    }
    const float inv = 1.0f / fmaxf((float)(end - beg), 1.0f);
    float2* o = reinterpret_cast<float2*>(agg + (size_t)wave * D) + lane;
    *o = make_float2(acc.x * inv, acc.y * inv);
}

// --- Epilogue: out = agg @ Wn + x_dst @ Ws + (bn + bs) -----------------

__global__ void out_kernel(const float* __restrict__ agg,
                           const float* __restrict__ x_dst,
                           const float* __restrict__ Wn,   // [D][OUT]
                           const float* __restrict__ bn,
                           const float* __restrict__ Ws,   // [D][OUT]
                           const float* __restrict__ bs,
                           float* __restrict__ out,
                           int N) {
    __shared__ float aggL[ROWS_PER_BLOCK][D];
    __shared__ float xdL[ROWS_PER_BLOCK][D];
    const int n = threadIdx.x;             // output column 0..127
    const int row0 = blockIdx.x * ROWS_PER_BLOCK;

    #pragma unroll
    for (int r = 0; r < ROWS_PER_BLOCK; ++r) {
        int row = row0 + r;
        float a = 0.f, xv = 0.f;
        if (row < N) {
            a  = agg[(long long)row * D + n];
            xv = x_dst[(long long)row * D + n];
        }
        aggL[r][n] = a;
        xdL[r][n]  = xv;
    }
    __syncthreads();

    const float b = bn[n] + bs[n];
    float acc[ROWS_PER_BLOCK];
    #pragma unroll
    for (int r = 0; r < ROWS_PER_BLOCK; ++r) acc[r] = b;

    for (int k = 0; k < D; ++k) {
        float wn = Wn[k * OUT_D + n];
        float ws = Ws[k * OUT_D + n];
        #pragma unroll
        for (int r = 0; r < ROWS_PER_BLOCK; ++r) {
            acc[r] = fmaf(aggL[r][k], wn, fmaf(xdL[r][k], ws, acc[r]));
        }
    }

    #pragma unroll
    for (int r = 0; r < ROWS_PER_BLOCK; ++r) {
        int row = row0 + r;
        if (row < N) out[(long long)row * OUT_D + n] = acc[r];
    }
}

extern "C" void kernel_launch(void* const* d_in, const int* in_sizes, int n_in,
                              void* d_out, int out_size, void* d_ws, size_t ws_size,
                              hipStream_t stream) {
    const float* x_src    = (const float*)d_in[0];
    const float* x_dst    = (const float*)d_in[1];
    const int*   edge_src = (const int*)d_in[2];
    const int*   edge_dst = (const int*)d_in[3];
    const float* Wn = (const float*)d_in[5];
    const float* bn = (const float*)d_in[6];
    const float* Ws = (const float*)d_in[7];
    const float* bs = (const float*)d_in[8];

    const int E = in_sizes[2];
    const int N = in_sizes[1] / D;   // num_dst

    // Workspace layout:
    //   agg:     N*D floats   (counts/cursor alias its first 2N ints — they are
    //                          dead before gather_kernel writes agg)
    //   offsets: N+1 ints
    //   eidx:    E ints
    float* agg     = (float*)d_ws;
    int*   counts  = (int*)d_ws;            // [0, N)   of agg region
    int*   cursor  = ((int*)d_ws) + N;      // [N, 2N)  of agg region
    int*   offsets = (int*)(agg + (size_t)N * D);
    int*   eidx    = offsets + (N + 1);

    hipMemsetAsync(counts, 0, (size_t)N * sizeof(int), stream);

    const int T = 256;
    hist_kernel<<<(E + T - 1) / T, T, 0, stream>>>(edge_dst, counts, E);
    scan_kernel<<<1, SCAN_THREADS, 0, stream>>>(counts, offsets, cursor, N, E);
    fill_kernel<<<(E + T - 1) / T, T, 0, stream>>>(edge_src, edge_dst, cursor, eidx, E);

    // one wave (64 lanes) per dst row, 4 waves per block
    int gblocks = (N + 3) / 4;
    gather_kernel<<<gblocks, 256, 0, stream>>>(x_src, offsets, eidx, agg, N);

    int oblocks = (N + ROWS_PER_BLOCK - 1) / ROWS_PER_BLOCK;
    out_kernel<<<oblocks, OUT_D, 0, stream>>>(
        agg, x_dst, Wn, bn, Ws, bs, (float*)d_out, N);
}

// Round 3
// 324.817 us; speedup vs baseline: 4.6151x; 1.1968x over previous
//
#include <hip/hip_runtime.h>

#define D 128
#define D4 32            // D in float4 units
#define SCAN_THREADS 1024
#define TM 64            // GEMM rows per block

// --- CSR build stage ---------------------------------------------------

__global__ void hist_kernel(const int* __restrict__ edge_dst,
                            int* __restrict__ counts, int E) {
    int e = blockIdx.x * blockDim.x + threadIdx.x;
    if (e < E) atomicAdd(&counts[edge_dst[e]], 1);
}

__global__ void scan_kernel(const int* __restrict__ counts,
                            int* __restrict__ offsets,
                            int* __restrict__ cursor, int N, int E) {
    __shared__ int sums[SCAN_THREADS];
    const int t = threadIdx.x;
    const int chunk = (N + SCAN_THREADS - 1) / SCAN_THREADS;
    const int lo = t * chunk;
    const int hi = min(lo + chunk, N);
    int s = 0;
    for (int i = lo; i < hi; ++i) s += counts[i];
    sums[t] = s;
    __syncthreads();
    for (int ofs = 1; ofs < SCAN_THREADS; ofs <<= 1) {
        int v = (t >= ofs) ? sums[t - ofs] : 0;
        __syncthreads();
        sums[t] += v;
        __syncthreads();
    }
    int run = (t == 0) ? 0 : sums[t - 1];
    for (int i = lo; i < hi; ++i) {
        offsets[i] = run;
        cursor[i]  = run;
        run += counts[i];
    }
    if (t == SCAN_THREADS - 1) offsets[N] = E;
}

__global__ void fill_kernel(const int* __restrict__ edge_src,
                            const int* __restrict__ edge_dst,
                            int* __restrict__ cursor,
                            int* __restrict__ eidx, int E) {
    int e = blockIdx.x * blockDim.x + threadIdx.x;
    if (e < E) {
        int pos = atomicAdd(&cursor[edge_dst[e]], 1);
        eidx[pos] = edge_src[e];
    }
}

// --- Dense GEMM: C[M][128] = A[M][128] @ W[128][128] (+ b0 + b1) -------
// 256 threads, 64 rows/block, thread owns 8 rows x 4 cols.
__global__ __launch_bounds__(256) void gemm128_kernel(
    const float* __restrict__ A,
    const float* __restrict__ W,
    const float* __restrict__ b0,   // nullable
    const float* __restrict__ b1,   // nullable
    float* __restrict__ C,
    int M) {
    __shared__ float4 At[TM * D4];      // 32 KB
    const int t = threadIdx.x;
    const int row0 = blockIdx.x * TM;
    const float4* Av = (const float4*)A;
    const float4* Wv = (const float4*)W;

    #pragma unroll
    for (int i = 0; i < 8; ++i) {
        int vi = t + i * 256;
        int r  = vi >> 5;
        int c4 = vi & 31;
        int sr = min(row0 + r, M - 1);
        At[vi] = Av[(size_t)sr * D4 + c4];
    }
    __syncthreads();

    const int tc = t & 31;          // float4 column index
    const int tr = (t >> 5) * 8;    // first of 8 rows

    float4 bias = make_float4(0.f, 0.f, 0.f, 0.f);
    if (b0) {
        float4 v0 = ((const float4*)b0)[tc];
        float4 v1 = ((const float4*)b1)[tc];
        bias = make_float4(v0.x + v1.x, v0.y + v1.y, v0.z + v1.z, v0.w + v1.w);
    }
    float4 acc[8];
    #pragma unroll
    for (int r = 0; r < 8; ++r) acc[r] = bias;

    for (int k4 = 0; k4 < D4; ++k4) {
        float4 w0 = Wv[(k4 * 4 + 0) * D4 + tc];
        float4 w1 = Wv[(k4 * 4 + 1) * D4 + tc];
        float4 w2 = Wv[(k4 * 4 + 2) * D4 + tc];
        float4 w3 = Wv[(k4 * 4 + 3) * D4 + tc];
        #pragma unroll
        for (int r = 0; r < 8; ++r) {
            float4 a = At[(tr + r) * D4 + k4];
            acc[r].x = fmaf(a.x, w0.x, acc[r].x);
            acc[r].x = fmaf(a.y, w1.x, acc[r].x);
            acc[r].x = fmaf(a.z, w2.x, acc[r].x);
            acc[r].x = fmaf(a.w, w3.x, acc[r].x);
            acc[r].y = fmaf(a.x, w0.y, acc[r].y);
            acc[r].y = fmaf(a.y, w1.y, acc[r].y);
            acc[r].y = fmaf(a.z, w2.y, acc[r].y);
            acc[r].y = fmaf(a.w, w3.y, acc[r].y);
            acc[r].z = fmaf(a.x, w0.z, acc[r].z);
            acc[r].z = fmaf(a.y, w1.z, acc[r].z);
            acc[r].z = fmaf(a.z, w2.z, acc[r].z);
            acc[r].z = fmaf(a.w, w3.z, acc[r].z);
            acc[r].w = fmaf(a.x, w0.w, acc[r].w);
            acc[r].w = fmaf(a.y, w1.w, acc[r].w);
            acc[r].w = fmaf(a.z, w2.w, acc[r].w);
            acc[r].w = fmaf(a.w, w3.w, acc[r].w);
        }
    }

    #pragma unroll
    for (int r = 0; r < 8; ++r) {
        int row = row0 + tr + r;
        if (row < M) ((float4*)C)[(size_t)row * D4 + tc] = acc[r];
    }
}

// --- Gather: out[d] += mean over edges of y_src[eidx] ------------------
// One wave per dst row; half-wave per edge (32 lanes x float4 = 512 B row),
// so each iteration covers 2 edges with one VMEM instr per lane.
__global__ void gather_out_kernel(const float* __restrict__ y_src,
                                  const int* __restrict__ offsets,
                                  const int* __restrict__ eidx,
                                  float* __restrict__ out, int N) {
    const int wave = (int)(((long long)blockIdx.x * blockDim.x + threadIdx.x) >> 6);
    const int lane = threadIdx.x & 63;
    if (wave >= N) return;
    const int h = lane >> 5;     // which edge of the pair
    const int c = lane & 31;     // float4 chunk within the row
    const int beg = offsets[wave];
    const int end = offsets[wave + 1];
    float4 acc = make_float4(0.f, 0.f, 0.f, 0.f);
    for (int i = beg + h; i < end; i += 2) {
        int s = eidx[i];
        const float4 v = *reinterpret_cast<const float4*>(
            y_src + (size_t)s * D + c * 4);
        acc.x += v.x; acc.y += v.y; acc.z += v.z; acc.w += v.w;
    }
    acc.x += __shfl_down(acc.x, 32);
    acc.y += __shfl_down(acc.y, 32);
    acc.z += __shfl_down(acc.z, 32);
    acc.w += __shfl_down(acc.w, 32);
    if (h == 0) {
        const float inv = 1.0f / fmaxf((float)(end - beg), 1.0f);
        float4* o = reinterpret_cast<float4*>(out + (size_t)wave * D) + c;
        float4 cur = *o;
        cur.x = fmaf(acc.x, inv, cur.x);
        cur.y = fmaf(acc.y, inv, cur.y);
        cur.z = fmaf(acc.z, inv, cur.z);
        cur.w = fmaf(acc.w, inv, cur.w);
        *o = cur;
    }
}

extern "C" void kernel_launch(void* const* d_in, const int* in_sizes, int n_in,
                              void* d_out, int out_size, void* d_ws, size_t ws_size,
                              hipStream_t stream) {
    const float* x_src    = (const float*)d_in[0];
    const float* x_dst    = (const float*)d_in[1];
    const int*   edge_src = (const int*)d_in[2];
    const int*   edge_dst = (const int*)d_in[3];
    const float* Wn = (const float*)d_in[5];
    const float* bn = (const float*)d_in[6];
    const float* Ws = (const float*)d_in[7];
    const float* bs = (const float*)d_in[8];

    const int E     = in_sizes[2];
    const int N     = in_sizes[1] / D;   // num_dst
    const int M_SRC = in_sizes[0] / D;   // num_src

    // ws layout: [y_src: M_SRC*D floats][offsets: N+1][eidx: E]
    // counts/cursor alias the head of y_src (dead before gemm_src writes it).
    float* y_src   = (float*)d_ws;
    int*   counts  = (int*)d_ws;
    int*   cursor  = ((int*)d_ws) + N;
    int*   offsets = (int*)(y_src + (size_t)M_SRC * D);
    int*   eidx    = offsets + (N + 1);

    hipMemsetAsync(counts, 0, (size_t)N * sizeof(int), stream);

    const int T = 256;
    hist_kernel<<<(E + T - 1) / T, T, 0, stream>>>(edge_dst, counts, E);
    scan_kernel<<<1, SCAN_THREADS, 0, stream>>>(counts, offsets, cursor, N, E);
    fill_kernel<<<(E + T - 1) / T, T, 0, stream>>>(edge_src, edge_dst, cursor, eidx, E);

    // y_src = x_src @ Wn  (no bias); overwrites the counts/cursor alias (dead)
    gemm128_kernel<<<(M_SRC + TM - 1) / TM, T, 0, stream>>>(
        x_src, Wn, nullptr, nullptr, y_src, M_SRC);
    // out = x_dst @ Ws + bn + bs
    gemm128_kernel<<<(N + TM - 1) / TM, T, 0, stream>>>(
        x_dst, Ws, bn, bs, (float*)d_out, N);

    // out += mean of projected neighbor rows
    gather_out_kernel<<<(N + 3) / 4, T, 0, stream>>>(
        y_src, offsets, eidx, (float*)d_out, N);
}

// Round 4
// 225.018 us; speedup vs baseline: 6.6620x; 1.4435x over previous
//
#include <hip/hip_runtime.h>

#define D 128
#define D4 32            // D in float4 units
#define TM 64            // GEMM rows per block
#define SCAN_CHUNK 1024  // elements per scan block

// --- CSR build stage ---------------------------------------------------

__global__ void hist_kernel(const int* __restrict__ edge_dst,
                            int* __restrict__ counts, int E) {
    int e = blockIdx.x * blockDim.x + threadIdx.x;
    if (e < E) atomicAdd(&counts[edge_dst[e]], 1);
}

// Step 1: per-chunk totals. 256 threads/block, chunk = 1024 counts.
__global__ __launch_bounds__(256) void block_sum_kernel(
    const int* __restrict__ counts, int* __restrict__ blockSums, int N) {
    __shared__ int red[4];
    const int t = threadIdx.x;
    const int base = blockIdx.x * SCAN_CHUNK;
    int s = 0;
    #pragma unroll
    for (int i = 0; i < SCAN_CHUNK / 256; ++i) {
        int idx = base + t + i * 256;
        if (idx < N) s += counts[idx];
    }
    #pragma unroll
    for (int ofs = 32; ofs > 0; ofs >>= 1) s += __shfl_down(s, ofs);
    if ((t & 63) == 0) red[t >> 6] = s;
    __syncthreads();
    if (t == 0) blockSums[blockIdx.x] = red[0] + red[1] + red[2] + red[3];
}

// Step 2: exclusive scan of the (<=256) chunk totals; also offsets[N]=E.
__global__ __launch_bounds__(256) void scan_sums_kernel(
    int* __restrict__ blockSums, int nb,
    int* __restrict__ offsets, int N, int E) {
    __shared__ int buf[256];
    const int t = threadIdx.x;
    const int orig = (t < nb) ? blockSums[t] : 0;
    buf[t] = orig;
    __syncthreads();
    for (int ofs = 1; ofs < 256; ofs <<= 1) {
        int v = (t >= ofs) ? buf[t - ofs] : 0;
        __syncthreads();
        buf[t] += v;
        __syncthreads();
    }
    if (t < nb) blockSums[t] = buf[t] - orig;   // exclusive
    if (t == 0) offsets[N] = E;
}

// Step 3: per-chunk exclusive scan + chunk base -> offsets & cursor.
__global__ __launch_bounds__(SCAN_CHUNK) void scan_final_kernel(
    const int* __restrict__ counts, const int* __restrict__ blockSums,
    int* __restrict__ offsets, int* __restrict__ cursor, int N) {
    __shared__ int buf[SCAN_CHUNK];
    const int t = threadIdx.x;
    const int idx = blockIdx.x * SCAN_CHUNK + t;
    const int v = (idx < N) ? counts[idx] : 0;
    buf[t] = v;
    __syncthreads();
    for (int ofs = 1; ofs < SCAN_CHUNK; ofs <<= 1) {
        int u = (t >= ofs) ? buf[t - ofs] : 0;
        __syncthreads();
        buf[t] += u;
        __syncthreads();
    }
    if (idx < N) {
        int excl = buf[t] - v + blockSums[blockIdx.x];
        offsets[idx] = excl;
        cursor[idx]  = excl;
    }
}

__global__ void fill_kernel(const int* __restrict__ edge_src,
                            const int* __restrict__ edge_dst,
                            int* __restrict__ cursor,
                            int* __restrict__ eidx, int E) {
    int e = blockIdx.x * blockDim.x + threadIdx.x;
    if (e < E) {
        int pos = atomicAdd(&cursor[edge_dst[e]], 1);
        eidx[pos] = edge_src[e];
    }
}

// --- Dense GEMM: C[M][128] = A[M][128] @ W[128][128] (+ b0 + b1) -------
__global__ __launch_bounds__(256) void gemm128_kernel(
    const float* __restrict__ A,
    const float* __restrict__ W,
    const float* __restrict__ b0,   // nullable
    const float* __restrict__ b1,   // nullable
    float* __restrict__ C,
    int M) {
    __shared__ float4 At[TM * D4];      // 32 KB
    const int t = threadIdx.x;
    const int row0 = blockIdx.x * TM;
    const float4* Av = (const float4*)A;
    const float4* Wv = (const float4*)W;

    #pragma unroll
    for (int i = 0; i < 8; ++i) {
        int vi = t + i * 256;
        int r  = vi >> 5;
        int c4 = vi & 31;
        int sr = min(row0 + r, M - 1);
        At[vi] = Av[(size_t)sr * D4 + c4];
    }
    __syncthreads();

    const int tc = t & 31;          // float4 column index
    const int tr = (t >> 5) * 8;    // first of 8 rows

    float4 bias = make_float4(0.f, 0.f, 0.f, 0.f);
    if (b0) {
        float4 v0 = ((const float4*)b0)[tc];
        float4 v1 = ((const float4*)b1)[tc];
        bias = make_float4(v0.x + v1.x, v0.y + v1.y, v0.z + v1.z, v0.w + v1.w);
    }
    float4 acc[8];
    #pragma unroll
    for (int r = 0; r < 8; ++r) acc[r] = bias;

    for (int k4 = 0; k4 < D4; ++k4) {
        float4 w0 = Wv[(k4 * 4 + 0) * D4 + tc];
        float4 w1 = Wv[(k4 * 4 + 1) * D4 + tc];
        float4 w2 = Wv[(k4 * 4 + 2) * D4 + tc];
        float4 w3 = Wv[(k4 * 4 + 3) * D4 + tc];
        #pragma unroll
        for (int r = 0; r < 8; ++r) {
            float4 a = At[(tr + r) * D4 + k4];
            acc[r].x = fmaf(a.x, w0.x, acc[r].x);
            acc[r].x = fmaf(a.y, w1.x, acc[r].x);
            acc[r].x = fmaf(a.z, w2.x, acc[r].x);
            acc[r].x = fmaf(a.w, w3.x, acc[r].x);
            acc[r].y = fmaf(a.x, w0.y, acc[r].y);
            acc[r].y = fmaf(a.y, w1.y, acc[r].y);
            acc[r].y = fmaf(a.z, w2.y, acc[r].y);
            acc[r].y = fmaf(a.w, w3.y, acc[r].y);
            acc[r].z = fmaf(a.x, w0.z, acc[r].z);
            acc[r].z = fmaf(a.y, w1.z, acc[r].z);
            acc[r].z = fmaf(a.z, w2.z, acc[r].z);
            acc[r].z = fmaf(a.w, w3.z, acc[r].z);
            acc[r].w = fmaf(a.x, w0.w, acc[r].w);
            acc[r].w = fmaf(a.y, w1.w, acc[r].w);
            acc[r].w = fmaf(a.z, w2.w, acc[r].w);
            acc[r].w = fmaf(a.w, w3.w, acc[r].w);
        }
    }

    #pragma unroll
    for (int r = 0; r < 8; ++r) {
        int row = row0 + tr + r;
        if (row < M) ((float4*)C)[(size_t)row * D4 + tc] = acc[r];
    }
}

// --- Gather: out[d] += mean over edges of y_src[eidx] ------------------
__global__ void gather_out_kernel(const float* __restrict__ y_src,
                                  const int* __restrict__ offsets,
                                  const int* __restrict__ eidx,
                                  float* __restrict__ out, int N) {
    const int wave = (int)(((long long)blockIdx.x * blockDim.x + threadIdx.x) >> 6);
    const int lane = threadIdx.x & 63;
    if (wave >= N) return;
    const int h = lane >> 5;     // which edge of the pair
    const int c = lane & 31;     // float4 chunk within the row
    const int beg = offsets[wave];
    const int end = offsets[wave + 1];
    float4 acc = make_float4(0.f, 0.f, 0.f, 0.f);
    for (int i = beg + h; i < end; i += 2) {
        int s = eidx[i];
        const float4 v = *reinterpret_cast<const float4*>(
            y_src + (size_t)s * D + c * 4);
        acc.x += v.x; acc.y += v.y; acc.z += v.z; acc.w += v.w;
    }
    acc.x += __shfl_down(acc.x, 32);
    acc.y += __shfl_down(acc.y, 32);
    acc.z += __shfl_down(acc.z, 32);
    acc.w += __shfl_down(acc.w, 32);
    if (h == 0) {
        const float inv = 1.0f / fmaxf((float)(end - beg), 1.0f);
        float4* o = reinterpret_cast<float4*>(out + (size_t)wave * D) + c;
        float4 cur = *o;
        cur.x = fmaf(acc.x, inv, cur.x);
        cur.y = fmaf(acc.y, inv, cur.y);
        cur.z = fmaf(acc.z, inv, cur.z);
        cur.w = fmaf(acc.w, inv, cur.w);
        *o = cur;
    }
}

extern "C" void kernel_launch(void* const* d_in, const int* in_sizes, int n_in,
                              void* d_out, int out_size, void* d_ws, size_t ws_size,
                              hipStream_t stream) {
    const float* x_src    = (const float*)d_in[0];
    const float* x_dst    = (const float*)d_in[1];
    const int*   edge_src = (const int*)d_in[2];
    const int*   edge_dst = (const int*)d_in[3];
    const float* Wn = (const float*)d_in[5];
    const float* bn = (const float*)d_in[6];
    const float* Ws = (const float*)d_in[7];
    const float* bs = (const float*)d_in[8];

    const int E     = in_sizes[2];
    const int N     = in_sizes[1] / D;   // num_dst
    const int M_SRC = in_sizes[0] / D;   // num_src

    // ws layout: [y_src: M_SRC*D floats][offsets: N+1][eidx: E][counts: N]
    //            [cursor: N][blockSums: nb]
    float* y_src    = (float*)d_ws;
    int*   offsets  = (int*)(y_src + (size_t)M_SRC * D);
    int*   eidx     = offsets + (N + 1);
    int*   counts   = eidx + E;
    int*   cursor   = counts + N;
    int*   blockSums = cursor + N;

    const int nb = (N + SCAN_CHUNK - 1) / SCAN_CHUNK;   // <=256 supported

    hipMemsetAsync(counts, 0, (size_t)N * sizeof(int), stream);

    const int T = 256;
    hist_kernel<<<(E + T - 1) / T, T, 0, stream>>>(edge_dst, counts, E);
    block_sum_kernel<<<nb, 256, 0, stream>>>(counts, blockSums, N);
    scan_sums_kernel<<<1, 256, 0, stream>>>(blockSums, nb, offsets, N, E);
    scan_final_kernel<<<nb, SCAN_CHUNK, 0, stream>>>(counts, blockSums, offsets, cursor, N);
    fill_kernel<<<(E + T - 1) / T, T, 0, stream>>>(edge_src, edge_dst, cursor, eidx, E);

    // y_src = x_src @ Wn  (no bias)
    gemm128_kernel<<<(M_SRC + TM - 1) / TM, T, 0, stream>>>(
        x_src, Wn, nullptr, nullptr, y_src, M_SRC);
    // out = x_dst @ Ws + bn + bs
    gemm128_kernel<<<(N + TM - 1) / TM, T, 0, stream>>>(
        x_dst, Ws, bn, bs, (float*)d_out, N);

    // out += mean of projected neighbor rows
    gather_out_kernel<<<(N + 3) / 4, T, 0, stream>>>(
        y_src, offsets, eidx, (float*)d_out, N);
}

// Round 5
// 205.012 us; speedup vs baseline: 7.3121x; 1.0976x over previous
//
#include <hip/hip_runtime.h>

#define D 128
#define D4 32            // D in float4 units
#define TM 64            // GEMM rows per block
#define SCAN_CHUNK 1024  // elements per scan block

// --- bf16 helpers ------------------------------------------------------

__device__ __forceinline__ unsigned short f32_to_bf16(float x) {
    unsigned u = __float_as_uint(x);
    u += 0x7FFFu + ((u >> 16) & 1u);   // round-to-nearest-even
    return (unsigned short)(u >> 16);
}
__device__ __forceinline__ float bf16_to_f32(unsigned short h) {
    return __uint_as_float(((unsigned)h) << 16);
}

// --- CSR build stage ---------------------------------------------------

__global__ void hist_kernel(const int* __restrict__ edge_dst,
                            int* __restrict__ counts, int E) {
    int e = blockIdx.x * blockDim.x + threadIdx.x;
    if (e < E) atomicAdd(&counts[edge_dst[e]], 1);
}

__global__ __launch_bounds__(256) void block_sum_kernel(
    const int* __restrict__ counts, int* __restrict__ blockSums, int N) {
    __shared__ int red[4];
    const int t = threadIdx.x;
    const int base = blockIdx.x * SCAN_CHUNK;
    int s = 0;
    #pragma unroll
    for (int i = 0; i < SCAN_CHUNK / 256; ++i) {
        int idx = base + t + i * 256;
        if (idx < N) s += counts[idx];
    }
    #pragma unroll
    for (int ofs = 32; ofs > 0; ofs >>= 1) s += __shfl_down(s, ofs);
    if ((t & 63) == 0) red[t >> 6] = s;
    __syncthreads();
    if (t == 0) blockSums[blockIdx.x] = red[0] + red[1] + red[2] + red[3];
}

__global__ __launch_bounds__(256) void scan_sums_kernel(
    int* __restrict__ blockSums, int nb,
    int* __restrict__ offsets, int N, int E) {
    __shared__ int buf[256];
    const int t = threadIdx.x;
    const int orig = (t < nb) ? blockSums[t] : 0;
    buf[t] = orig;
    __syncthreads();
    for (int ofs = 1; ofs < 256; ofs <<= 1) {
        int v = (t >= ofs) ? buf[t - ofs] : 0;
        __syncthreads();
        buf[t] += v;
        __syncthreads();
    }
    if (t < nb) blockSums[t] = buf[t] - orig;   // exclusive
    if (t == 0) offsets[N] = E;
}

__global__ __launch_bounds__(SCAN_CHUNK) void scan_final_kernel(
    const int* __restrict__ counts, const int* __restrict__ blockSums,
    int* __restrict__ offsets, int* __restrict__ cursor, int N) {
    __shared__ int buf[SCAN_CHUNK];
    const int t = threadIdx.x;
    const int idx = blockIdx.x * SCAN_CHUNK + t;
    const int v = (idx < N) ? counts[idx] : 0;
    buf[t] = v;
    __syncthreads();
    for (int ofs = 1; ofs < SCAN_CHUNK; ofs <<= 1) {
        int u = (t >= ofs) ? buf[t - ofs] : 0;
        __syncthreads();
        buf[t] += u;
        __syncthreads();
    }
    if (idx < N) {
        int excl = buf[t] - v + blockSums[blockIdx.x];
        offsets[idx] = excl;
        cursor[idx]  = excl;
    }
}

__global__ void fill_kernel(const int* __restrict__ edge_src,
                            const int* __restrict__ edge_dst,
                            int* __restrict__ cursor,
                            int* __restrict__ eidx, int E) {
    int e = blockIdx.x * blockDim.x + threadIdx.x;
    if (e < E) {
        int pos = atomicAdd(&cursor[edge_dst[e]], 1);
        eidx[pos] = edge_src[e];
    }
}

// --- Dense GEMM: C[M][128] = A[M][128] @ W[128][128] (+ b0 + b1) -------
// BF16OUT: write C as bf16 (row-major ushort) instead of fp32.
template <bool BF16OUT>
__global__ __launch_bounds__(256) void gemm128_kernel(
    const float* __restrict__ A,
    const float* __restrict__ W,
    const float* __restrict__ b0,   // nullable
    const float* __restrict__ b1,   // nullable
    void* __restrict__ Cout,
    int M) {
    __shared__ float4 At[TM * D4];      // 32 KB
    const int t = threadIdx.x;
    const int row0 = blockIdx.x * TM;
    const float4* Av = (const float4*)A;
    const float4* Wv = (const float4*)W;

    #pragma unroll
    for (int i = 0; i < 8; ++i) {
        int vi = t + i * 256;
        int r  = vi >> 5;
        int c4 = vi & 31;
        int sr = min(row0 + r, M - 1);
        At[vi] = Av[(size_t)sr * D4 + c4];
    }
    __syncthreads();

    const int tc = t & 31;          // float4 column index
    const int tr = (t >> 5) * 8;    // first of 8 rows

    float4 bias = make_float4(0.f, 0.f, 0.f, 0.f);
    if (b0) {
        float4 v0 = ((const float4*)b0)[tc];
        float4 v1 = ((const float4*)b1)[tc];
        bias = make_float4(v0.x + v1.x, v0.y + v1.y, v0.z + v1.z, v0.w + v1.w);
    }
    float4 acc[8];
    #pragma unroll
    for (int r = 0; r < 8; ++r) acc[r] = bias;

    for (int k4 = 0; k4 < D4; ++k4) {
        float4 w0 = Wv[(k4 * 4 + 0) * D4 + tc];
        float4 w1 = Wv[(k4 * 4 + 1) * D4 + tc];
        float4 w2 = Wv[(k4 * 4 + 2) * D4 + tc];
        float4 w3 = Wv[(k4 * 4 + 3) * D4 + tc];
        #pragma unroll
        for (int r = 0; r < 8; ++r) {
            float4 a = At[(tr + r) * D4 + k4];
            acc[r].x = fmaf(a.x, w0.x, acc[r].x);
            acc[r].x = fmaf(a.y, w1.x, acc[r].x);
            acc[r].x = fmaf(a.z, w2.x, acc[r].x);
            acc[r].x = fmaf(a.w, w3.x, acc[r].x);
            acc[r].y = fmaf(a.x, w0.y, acc[r].y);
            acc[r].y = fmaf(a.y, w1.y, acc[r].y);
            acc[r].y = fmaf(a.z, w2.y, acc[r].y);
            acc[r].y = fmaf(a.w, w3.y, acc[r].y);
            acc[r].z = fmaf(a.x, w0.z, acc[r].z);
            acc[r].z = fmaf(a.y, w1.z, acc[r].z);
            acc[r].z = fmaf(a.z, w2.z, acc[r].z);
            acc[r].z = fmaf(a.w, w3.z, acc[r].z);
            acc[r].w = fmaf(a.x, w0.w, acc[r].w);
            acc[r].w = fmaf(a.y, w1.w, acc[r].w);
            acc[r].w = fmaf(a.z, w2.w, acc[r].w);
            acc[r].w = fmaf(a.w, w3.w, acc[r].w);
        }
    }

    #pragma unroll
    for (int r = 0; r < 8; ++r) {
        int row = row0 + tr + r;
        if (row < M) {
            if (BF16OUT) {
                ushort4 p;
                p.x = f32_to_bf16(acc[r].x);
                p.y = f32_to_bf16(acc[r].y);
                p.z = f32_to_bf16(acc[r].z);
                p.w = f32_to_bf16(acc[r].w);
                ((ushort4*)Cout)[(size_t)row * D4 + tc] = p;
            } else {
                ((float4*)Cout)[(size_t)row * D4 + tc] = acc[r];
            }
        }
    }
}

// --- Gather: out[d] += mean over edges of y16[eidx] (bf16 rows) --------
// One wave per dst row; quarter-wave (16 lanes) per edge: 16 lanes x 16 B
// = 256 B = one bf16 row. 4 edges per wave-iteration.
__global__ void gather_out_kernel(const unsigned short* __restrict__ y16,
                                  const int* __restrict__ offsets,
                                  const int* __restrict__ eidx,
                                  float* __restrict__ out, int N) {
    const int wave = (int)(((long long)blockIdx.x * blockDim.x + threadIdx.x) >> 6);
    const int lane = threadIdx.x & 63;
    if (wave >= N) return;
    const int h = lane >> 4;     // which edge of the quad (0..3)
    const int c = lane & 15;     // 16B chunk within the row (8 bf16)
    const int beg = offsets[wave];
    const int end = offsets[wave + 1];

    float acc[8];
    #pragma unroll
    for (int j = 0; j < 8; ++j) acc[j] = 0.f;

    for (int i = beg + h; i < end; i += 4) {
        int s = eidx[i];
        const int4 v = *reinterpret_cast<const int4*>(y16 + (size_t)s * D + c * 8);
        const unsigned short* hs = (const unsigned short*)&v;
        #pragma unroll
        for (int j = 0; j < 8; ++j) acc[j] += bf16_to_f32(hs[j]);
    }

    #pragma unroll
    for (int j = 0; j < 8; ++j) {
        acc[j] += __shfl_down(acc[j], 32);
        acc[j] += __shfl_down(acc[j], 16);
    }

    if (h == 0) {
        const float inv = 1.0f / fmaxf((float)(end - beg), 1.0f);
        float4* o = reinterpret_cast<float4*>(out + (size_t)wave * D) + c * 2;
        float4 c0 = o[0], c1 = o[1];
        c0.x = fmaf(acc[0], inv, c0.x);
        c0.y = fmaf(acc[1], inv, c0.y);
        c0.z = fmaf(acc[2], inv, c0.z);
        c0.w = fmaf(acc[3], inv, c0.w);
        c1.x = fmaf(acc[4], inv, c1.x);
        c1.y = fmaf(acc[5], inv, c1.y);
        c1.z = fmaf(acc[6], inv, c1.z);
        c1.w = fmaf(acc[7], inv, c1.w);
        o[0] = c0;
        o[1] = c1;
    }
}

extern "C" void kernel_launch(void* const* d_in, const int* in_sizes, int n_in,
                              void* d_out, int out_size, void* d_ws, size_t ws_size,
                              hipStream_t stream) {
    const float* x_src    = (const float*)d_in[0];
    const float* x_dst    = (const float*)d_in[1];
    const int*   edge_src = (const int*)d_in[2];
    const int*   edge_dst = (const int*)d_in[3];
    const float* Wn = (const float*)d_in[5];
    const float* bn = (const float*)d_in[6];
    const float* Ws = (const float*)d_in[7];
    const float* bs = (const float*)d_in[8];

    const int E     = in_sizes[2];
    const int N     = in_sizes[1] / D;   // num_dst
    const int M_SRC = in_sizes[0] / D;   // num_src

    // ws layout: [y16: M_SRC*D ushort][offsets: N+1][eidx: E][counts: N]
    //            [cursor: N][blockSums: <=256]
    unsigned short* y16 = (unsigned short*)d_ws;
    int* offsets   = (int*)(y16 + (size_t)M_SRC * D);
    int* eidx      = offsets + (N + 1);
    int* counts    = eidx + E;
    int* cursor    = counts + N;
    int* blockSums = cursor + N;

    const int nb = (N + SCAN_CHUNK - 1) / SCAN_CHUNK;   // <=256 supported

    hipMemsetAsync(counts, 0, (size_t)N * sizeof(int), stream);

    const int T = 256;
    hist_kernel<<<(E + T - 1) / T, T, 0, stream>>>(edge_dst, counts, E);
    block_sum_kernel<<<nb, 256, 0, stream>>>(counts, blockSums, N);
    scan_sums_kernel<<<1, 256, 0, stream>>>(blockSums, nb, offsets, N, E);
    scan_final_kernel<<<nb, SCAN_CHUNK, 0, stream>>>(counts, blockSums, offsets, cursor, N);
    fill_kernel<<<(E + T - 1) / T, T, 0, stream>>>(edge_src, edge_dst, cursor, eidx, E);

    // y16 = bf16(x_src @ Wn)
    gemm128_kernel<true><<<(M_SRC + TM - 1) / TM, T, 0, stream>>>(
        x_src, Wn, nullptr, nullptr, y16, M_SRC);
    // out = x_dst @ Ws + bn + bs
    gemm128_kernel<false><<<(N + TM - 1) / TM, T, 0, stream>>>(
        x_dst, Ws, bn, bs, d_out, N);

    // out += mean of projected neighbor rows (bf16 rows, fp32 accum)
    gather_out_kernel<<<(N + 3) / 4, T, 0, stream>>>(
        y16, offsets, eidx, (float*)d_out, N);
}

// Round 6
// 158.584 us; speedup vs baseline: 9.4528x; 1.2928x over previous
//
#include <hip/hip_runtime.h>

#define D 128
#define D4 32            // D in float4 units
#define TM 64            // GEMM rows per block
#define CBITS 7          // 128 dsts per coarse bucket
#define CSIZE 128
#define MAXNB 512        // max coarse buckets supported (N <= 65536)
#define EPB 8192         // edges per partition block

// --- bf16 helpers ------------------------------------------------------

__device__ __forceinline__ unsigned short f32_to_bf16(float x) {
    unsigned u = __float_as_uint(x);
    u += 0x7FFFu + ((u >> 16) & 1u);   // round-to-nearest-even
    return (unsigned short)(u >> 16);
}
__device__ __forceinline__ float bf16_to_f32(unsigned short h) {
    return __uint_as_float(((unsigned)h) << 16);
}

// --- CSR build: two-level counting partition ---------------------------

// 1) coarse histogram (LDS-staged)
__global__ __launch_bounds__(256) void chist_kernel(
    const int* __restrict__ edge_dst, int* __restrict__ gcount, int E, int NB) {
    __shared__ int lh[MAXNB];
    for (int i = threadIdx.x; i < NB; i += 256) lh[i] = 0;
    __syncthreads();
    const int base = blockIdx.x * EPB;
    for (int i = threadIdx.x; i < EPB; i += 256) {
        int e = base + i;
        if (e < E) atomicAdd(&lh[edge_dst[e] >> CBITS], 1);
    }
    __syncthreads();
    for (int i = threadIdx.x; i < NB; i += 256) {
        int v = lh[i];
        if (v) atomicAdd(&gcount[i], v);
    }
}

// 2) scan coarse counts; prime bucket cursors; offsets[N]=E
__global__ __launch_bounds__(MAXNB) void cscan_kernel(
    const int* __restrict__ gcount, int* __restrict__ cOff,
    int* __restrict__ gcursor, int NB, int E,
    int* __restrict__ offsets, int N) {
    __shared__ int buf[MAXNB];
    const int t = threadIdx.x;
    const int v = (t < NB) ? gcount[t] : 0;
    buf[t] = v;
    __syncthreads();
    for (int ofs = 1; ofs < MAXNB; ofs <<= 1) {
        int u = (t >= ofs) ? buf[t - ofs] : 0;
        __syncthreads();
        buf[t] += u;
        __syncthreads();
    }
    if (t < NB) {
        int excl = buf[t] - v;
        cOff[t] = excl;
        gcursor[t] = excl;
    }
    if (t == 0) { cOff[NB] = E; offsets[N] = E; }
}

// 3) partition edges into coarse buckets as (src,dst) pairs
__global__ __launch_bounds__(256) void cfill_kernel(
    const int* __restrict__ edge_src, const int* __restrict__ edge_dst,
    int* __restrict__ gcursor, int2* __restrict__ pairs, int E, int NB) {
    __shared__ int lcount[MAXNB];
    __shared__ int lbase[MAXNB];
    for (int i = threadIdx.x; i < NB; i += 256) lcount[i] = 0;
    __syncthreads();
    const int base = blockIdx.x * EPB;
    for (int i = threadIdx.x; i < EPB; i += 256) {
        int e = base + i;
        if (e < E) atomicAdd(&lcount[edge_dst[e] >> CBITS], 1);
    }
    __syncthreads();
    for (int i = threadIdx.x; i < NB; i += 256) {
        int v = lcount[i];
        lbase[i] = v ? atomicAdd(&gcursor[i], v) : 0;
    }
    __syncthreads();
    for (int i = threadIdx.x; i < NB; i += 256) lcount[i] = 0;   // reuse as cursor
    __syncthreads();
    for (int i = threadIdx.x; i < EPB; i += 256) {
        int e = base + i;
        if (e < E) {
            int d = edge_dst[e];
            int b = d >> CBITS;
            int p = lbase[b] + atomicAdd(&lcount[b], 1);
            pairs[p] = make_int2(edge_src[e], d);
        }
    }
}

// 4) per-bucket fine placement: offsets (coalesced) + eidx (bucket-local)
__global__ __launch_bounds__(256) void fine_kernel(
    const int2* __restrict__ pairs, const int* __restrict__ cOff,
    int* __restrict__ offsets, int* __restrict__ eidx, int N) {
    __shared__ int dcount[CSIZE];
    __shared__ int dbase[CSIZE];
    __shared__ int sbuf[CSIZE];
    const int b = blockIdx.x;
    const int d0 = b << CBITS;
    const int beg = cOff[b];
    const int end = cOff[b + 1];
    const int t = threadIdx.x;
    if (t < CSIZE) dcount[t] = 0;
    __syncthreads();
    for (int i = beg + t; i < end; i += 256)
        atomicAdd(&dcount[pairs[i].y - d0], 1);
    __syncthreads();
    if (t < CSIZE) sbuf[t] = dcount[t];
    __syncthreads();
    for (int ofs = 1; ofs < CSIZE; ofs <<= 1) {
        int u = (t < CSIZE && t >= ofs) ? sbuf[t - ofs] : 0;
        __syncthreads();
        if (t < CSIZE) sbuf[t] += u;
        __syncthreads();
    }
    if (t < CSIZE) {
        int excl = sbuf[t] - dcount[t];
        dbase[t] = excl;
        int d = d0 + t;
        if (d < N) offsets[d] = beg + excl;
    }
    __syncthreads();
    if (t < CSIZE) dcount[t] = dbase[t];     // reuse as local cursor
    __syncthreads();
    for (int i = beg + t; i < end; i += 256) {
        int2 p = pairs[i];
        int pos = beg + atomicAdd(&dcount[p.y - d0], 1);
        eidx[pos] = p.x;
    }
}

// --- Dense GEMM: C[M][128] = A[M][128] @ W[128][128] (+ b0 + b1) -------
template <bool BF16OUT>
__global__ __launch_bounds__(256) void gemm128_kernel(
    const float* __restrict__ A,
    const float* __restrict__ W,
    const float* __restrict__ b0,   // nullable
    const float* __restrict__ b1,   // nullable
    void* __restrict__ Cout,
    int M) {
    __shared__ float4 At[TM * D4];      // 32 KB
    const int t = threadIdx.x;
    const int row0 = blockIdx.x * TM;
    const float4* Av = (const float4*)A;
    const float4* Wv = (const float4*)W;

    #pragma unroll
    for (int i = 0; i < 8; ++i) {
        int vi = t + i * 256;
        int r  = vi >> 5;
        int c4 = vi & 31;
        int sr = min(row0 + r, M - 1);
        At[vi] = Av[(size_t)sr * D4 + c4];
    }
    __syncthreads();

    const int tc = t & 31;          // float4 column index
    const int tr = (t >> 5) * 8;    // first of 8 rows

    float4 bias = make_float4(0.f, 0.f, 0.f, 0.f);
    if (b0) {
        float4 v0 = ((const float4*)b0)[tc];
        float4 v1 = ((const float4*)b1)[tc];
        bias = make_float4(v0.x + v1.x, v0.y + v1.y, v0.z + v1.z, v0.w + v1.w);
    }
    float4 acc[8];
    #pragma unroll
    for (int r = 0; r < 8; ++r) acc[r] = bias;

    for (int k4 = 0; k4 < D4; ++k4) {
        float4 w0 = Wv[(k4 * 4 + 0) * D4 + tc];
        float4 w1 = Wv[(k4 * 4 + 1) * D4 + tc];
        float4 w2 = Wv[(k4 * 4 + 2) * D4 + tc];
        float4 w3 = Wv[(k4 * 4 + 3) * D4 + tc];
        #pragma unroll
        for (int r = 0; r < 8; ++r) {
            float4 a = At[(tr + r) * D4 + k4];
            acc[r].x = fmaf(a.x, w0.x, acc[r].x);
            acc[r].x = fmaf(a.y, w1.x, acc[r].x);
            acc[r].x = fmaf(a.z, w2.x, acc[r].x);
            acc[r].x = fmaf(a.w, w3.x, acc[r].x);
            acc[r].y = fmaf(a.x, w0.y, acc[r].y);
            acc[r].y = fmaf(a.y, w1.y, acc[r].y);
            acc[r].y = fmaf(a.z, w2.y, acc[r].y);
            acc[r].y = fmaf(a.w, w3.y, acc[r].y);
            acc[r].z = fmaf(a.x, w0.z, acc[r].z);
            acc[r].z = fmaf(a.y, w1.z, acc[r].z);
            acc[r].z = fmaf(a.z, w2.z, acc[r].z);
            acc[r].z = fmaf(a.w, w3.z, acc[r].z);
            acc[r].w = fmaf(a.x, w0.w, acc[r].w);
            acc[r].w = fmaf(a.y, w1.w, acc[r].w);
            acc[r].w = fmaf(a.z, w2.w, acc[r].w);
            acc[r].w = fmaf(a.w, w3.w, acc[r].w);
        }
    }

    #pragma unroll
    for (int r = 0; r < 8; ++r) {
        int row = row0 + tr + r;
        if (row < M) {
            if (BF16OUT) {
                ushort4 p;
                p.x = f32_to_bf16(acc[r].x);
                p.y = f32_to_bf16(acc[r].y);
                p.z = f32_to_bf16(acc[r].z);
                p.w = f32_to_bf16(acc[r].w);
                ((ushort4*)Cout)[(size_t)row * D4 + tc] = p;
            } else {
                ((float4*)Cout)[(size_t)row * D4 + tc] = acc[r];
            }
        }
    }
}

// --- Gather: out[d] += mean over edges of y16[eidx] (bf16 rows) --------
__global__ void gather_out_kernel(const unsigned short* __restrict__ y16,
                                  const int* __restrict__ offsets,
                                  const int* __restrict__ eidx,
                                  float* __restrict__ out, int N) {
    const int wave = (int)(((long long)blockIdx.x * blockDim.x + threadIdx.x) >> 6);
    const int lane = threadIdx.x & 63;
    if (wave >= N) return;
    const int h = lane >> 4;     // which edge of the quad (0..3)
    const int c = lane & 15;     // 16B chunk within the row (8 bf16)
    const int beg = offsets[wave];
    const int end = offsets[wave + 1];

    float acc[8];
    #pragma unroll
    for (int j = 0; j < 8; ++j) acc[j] = 0.f;

    for (int i = beg + h; i < end; i += 4) {
        int s = eidx[i];
        const int4 v = *reinterpret_cast<const int4*>(y16 + (size_t)s * D + c * 8);
        const unsigned short* hs = (const unsigned short*)&v;
        #pragma unroll
        for (int j = 0; j < 8; ++j) acc[j] += bf16_to_f32(hs[j]);
    }

    #pragma unroll
    for (int j = 0; j < 8; ++j) {
        acc[j] += __shfl_down(acc[j], 32);
        acc[j] += __shfl_down(acc[j], 16);
    }

    if (h == 0) {
        const float inv = 1.0f / fmaxf((float)(end - beg), 1.0f);
        float4* o = reinterpret_cast<float4*>(out + (size_t)wave * D) + c * 2;
        float4 c0 = o[0], c1 = o[1];
        c0.x = fmaf(acc[0], inv, c0.x);
        c0.y = fmaf(acc[1], inv, c0.y);
        c0.z = fmaf(acc[2], inv, c0.z);
        c0.w = fmaf(acc[3], inv, c0.w);
        c1.x = fmaf(acc[4], inv, c1.x);
        c1.y = fmaf(acc[5], inv, c1.y);
        c1.z = fmaf(acc[6], inv, c1.z);
        c1.w = fmaf(acc[7], inv, c1.w);
        o[0] = c0;
        o[1] = c1;
    }
}

extern "C" void kernel_launch(void* const* d_in, const int* in_sizes, int n_in,
                              void* d_out, int out_size, void* d_ws, size_t ws_size,
                              hipStream_t stream) {
    const float* x_src    = (const float*)d_in[0];
    const float* x_dst    = (const float*)d_in[1];
    const int*   edge_src = (const int*)d_in[2];
    const int*   edge_dst = (const int*)d_in[3];
    const float* Wn = (const float*)d_in[5];
    const float* bn = (const float*)d_in[6];
    const float* Ws = (const float*)d_in[7];
    const float* bs = (const float*)d_in[8];

    const int E     = in_sizes[2];
    const int N     = in_sizes[1] / D;   // num_dst
    const int M_SRC = in_sizes[0] / D;   // num_src

    const int NB = (N + CSIZE - 1) >> CBITS;   // coarse buckets (<= MAXNB)

    // ws layout: [y16: M_SRC*D ushort][pairs: E int2][offsets: N+1]
    //            [eidx: E][gcount: NB][cOff: NB+1][gcursor: NB]
    unsigned short* y16 = (unsigned short*)d_ws;
    int2* pairs    = (int2*)(y16 + (size_t)M_SRC * D);
    int*  offsets  = (int*)(pairs + E);
    int*  eidx     = offsets + (N + 1);
    int*  gcount   = eidx + E;
    int*  cOff     = gcount + NB;
    int*  gcursor  = cOff + (NB + 1);

    hipMemsetAsync(gcount, 0, (size_t)NB * sizeof(int), stream);

    const int T = 256;
    const int pblocks = (E + EPB - 1) / EPB;
    chist_kernel<<<pblocks, T, 0, stream>>>(edge_dst, gcount, E, NB);
    cscan_kernel<<<1, MAXNB, 0, stream>>>(gcount, cOff, gcursor, NB, E, offsets, N);
    cfill_kernel<<<pblocks, T, 0, stream>>>(edge_src, edge_dst, gcursor, pairs, E, NB);
    fine_kernel<<<NB, T, 0, stream>>>(pairs, cOff, offsets, eidx, N);

    // y16 = bf16(x_src @ Wn)
    gemm128_kernel<true><<<(M_SRC + TM - 1) / TM, T, 0, stream>>>(
        x_src, Wn, nullptr, nullptr, y16, M_SRC);
    // out = x_dst @ Ws + bn + bs
    gemm128_kernel<false><<<(N + TM - 1) / TM, T, 0, stream>>>(
        x_dst, Ws, bn, bs, d_out, N);

    // out += mean of projected neighbor rows (bf16 rows, fp32 accum)
    gather_out_kernel<<<(N + 3) / 4, T, 0, stream>>>(
        y16, offsets, eidx, (float*)d_out, N);
}

// Round 7
// 131.722 us; speedup vs baseline: 11.3805x; 1.2039x over previous
//
#include <hip/hip_runtime.h>

#define D 128
#define D4 32            // D in float4 units
#define TM 64            // GEMM rows per block
#define CBITS 7          // 128 dsts per coarse bucket
#define CSIZE 128
#define MAXNB 512        // max coarse buckets (N <= 65536), max partition blocks

// --- bf16 helpers ------------------------------------------------------

__device__ __forceinline__ unsigned short f32_to_bf16(float x) {
    unsigned u = __float_as_uint(x);
    u += 0x7FFFu + ((u >> 16) & 1u);   // round-to-nearest-even
    return (unsigned short)(u >> 16);
}
__device__ __forceinline__ float bf16_to_f32(unsigned short h) {
    return __uint_as_float(((unsigned)h) << 16);
}

// --- CSR build: deterministic two-level counting partition -------------

// 1) per-block LDS histogram -> own row of Cmat (no global atomics, no init)
__global__ __launch_bounds__(256) void count_kernel(
    const int* __restrict__ edge_dst, int* __restrict__ Cmat,
    int E, int NB, int EPB) {
    __shared__ int lh[MAXNB];
    for (int i = threadIdx.x; i < NB; i += 256) lh[i] = 0;
    __syncthreads();
    const int base = blockIdx.x * EPB;
    const int lim  = min(base + EPB, E);
    for (int i = base + (int)threadIdx.x; i < lim; i += 256)
        atomicAdd(&lh[edge_dst[i] >> CBITS], 1);
    __syncthreads();
    int* row = Cmat + (size_t)blockIdx.x * NB;
    for (int i = threadIdx.x; i < NB; i += 256) row[i] = lh[i];
}

// 2) per-bucket scan over blocks: ColBase[b][j] excl-scan, colTotal[j]
__global__ __launch_bounds__(512) void colscan_kernel(
    const int* __restrict__ Cmat, int* __restrict__ ColBase,
    int* __restrict__ colTotal, int nblk, int NB) {
    __shared__ int buf[512];
    const int j = blockIdx.x;
    const int t = threadIdx.x;
    int v = (t < nblk) ? Cmat[(size_t)t * NB + j] : 0;
    buf[t] = v;
    __syncthreads();
    for (int ofs = 1; ofs < 512; ofs <<= 1) {
        int u = (t >= ofs) ? buf[t - ofs] : 0;
        __syncthreads();
        buf[t] += u;
        __syncthreads();
    }
    if (t < nblk) ColBase[(size_t)t * NB + j] = buf[t] - v;
    if (t == 511) colTotal[j] = buf[511];
}

// 3) scan bucket totals -> bucketBase, cOff; offsets[N]=E
__global__ __launch_bounds__(512) void totscan_kernel(
    const int* __restrict__ colTotal, int* __restrict__ bucketBase,
    int* __restrict__ cOff, int NB, int E,
    int* __restrict__ offsets, int N) {
    __shared__ int buf[512];
    const int t = threadIdx.x;
    int v = (t < NB) ? colTotal[t] : 0;
    buf[t] = v;
    __syncthreads();
    for (int ofs = 1; ofs < 512; ofs <<= 1) {
        int u = (t >= ofs) ? buf[t - ofs] : 0;
        __syncthreads();
        buf[t] += u;
        __syncthreads();
    }
    if (t < NB) {
        int ex = buf[t] - v;
        bucketBase[t] = ex;
        cOff[t] = ex;
    }
    if (t == 0) { cOff[NB] = E; offsets[N] = E; }
}

// 4) place edges into coarse buckets as packed (src<<7)|(dst&127)
__global__ __launch_bounds__(256) void place_kernel(
    const int* __restrict__ edge_src, const int* __restrict__ edge_dst,
    const int* __restrict__ bucketBase, const int* __restrict__ ColBase,
    int* __restrict__ packed, int E, int NB, int EPB) {
    __shared__ int lcur[MAXNB];
    const int b = blockIdx.x;
    for (int i = threadIdx.x; i < NB; i += 256)
        lcur[i] = bucketBase[i] + ColBase[(size_t)b * NB + i];
    __syncthreads();
    const int base = b * EPB;
    const int lim  = min(base + EPB, E);
    for (int i = base + (int)threadIdx.x; i < lim; i += 256) {
        int d  = edge_dst[i];
        int bk = d >> CBITS;
        int p  = atomicAdd(&lcur[bk], 1);
        packed[p] = (edge_src[i] << CBITS) | (d & (CSIZE - 1));
    }
}

// 5) per-bucket fine placement: offsets (coalesced) + eidx (bucket-local)
__global__ __launch_bounds__(256) void fine_kernel(
    const int* __restrict__ packed, const int* __restrict__ cOff,
    int* __restrict__ offsets, int* __restrict__ eidx, int N) {
    __shared__ int dcount[CSIZE];
    __shared__ int dbase[CSIZE];
    __shared__ int sbuf[CSIZE];
    const int b  = blockIdx.x;
    const int d0 = b << CBITS;
    const int beg = cOff[b];
    const int end = cOff[b + 1];
    const int t = threadIdx.x;
    if (t < CSIZE) dcount[t] = 0;
    __syncthreads();
    for (int i = beg + t; i < end; i += 256)
        atomicAdd(&dcount[packed[i] & (CSIZE - 1)], 1);
    __syncthreads();
    if (t < CSIZE) sbuf[t] = dcount[t];
    __syncthreads();
    for (int ofs = 1; ofs < CSIZE; ofs <<= 1) {
        int u = (t < CSIZE && t >= ofs) ? sbuf[t - ofs] : 0;
        __syncthreads();
        if (t < CSIZE) sbuf[t] += u;
        __syncthreads();
    }
    if (t < CSIZE) {
        int excl = sbuf[t] - dcount[t];
        dbase[t] = excl;
        int d = d0 + t;
        if (d < N) offsets[d] = beg + excl;
    }
    __syncthreads();
    if (t < CSIZE) dcount[t] = dbase[t];     // reuse as local cursor
    __syncthreads();
    for (int i = beg + t; i < end; i += 256) {
        int p = packed[i];
        int pos = beg + atomicAdd(&dcount[p & (CSIZE - 1)], 1);
        eidx[pos] = p >> CBITS;
    }
}

// --- Dense GEMM: C[M][128] = A[M][128] @ W[128][128] (+ b0 + b1) -------
template <bool BF16OUT>
__global__ __launch_bounds__(256) void gemm128_kernel(
    const float* __restrict__ A,
    const float* __restrict__ W,
    const float* __restrict__ b0,   // nullable
    const float* __restrict__ b1,   // nullable
    void* __restrict__ Cout,
    int M) {
    __shared__ float4 At[TM * D4];      // 32 KB
    const int t = threadIdx.x;
    const int row0 = blockIdx.x * TM;
    const float4* Av = (const float4*)A;
    const float4* Wv = (const float4*)W;

    #pragma unroll
    for (int i = 0; i < 8; ++i) {
        int vi = t + i * 256;
        int r  = vi >> 5;
        int c4 = vi & 31;
        int sr = min(row0 + r, M - 1);
        At[vi] = Av[(size_t)sr * D4 + c4];
    }
    __syncthreads();

    const int tc = t & 31;          // float4 column index
    const int tr = (t >> 5) * 8;    // first of 8 rows

    float4 bias = make_float4(0.f, 0.f, 0.f, 0.f);
    if (b0) {
        float4 v0 = ((const float4*)b0)[tc];
        float4 v1 = ((const float4*)b1)[tc];
        bias = make_float4(v0.x + v1.x, v0.y + v1.y, v0.z + v1.z, v0.w + v1.w);
    }
    float4 acc[8];
    #pragma unroll
    for (int r = 0; r < 8; ++r) acc[r] = bias;

    for (int k4 = 0; k4 < D4; ++k4) {
        float4 w0 = Wv[(k4 * 4 + 0) * D4 + tc];
        float4 w1 = Wv[(k4 * 4 + 1) * D4 + tc];
        float4 w2 = Wv[(k4 * 4 + 2) * D4 + tc];
        float4 w3 = Wv[(k4 * 4 + 3) * D4 + tc];
        #pragma unroll
        for (int r = 0; r < 8; ++r) {
            float4 a = At[(tr + r) * D4 + k4];
            acc[r].x = fmaf(a.x, w0.x, acc[r].x);
            acc[r].x = fmaf(a.y, w1.x, acc[r].x);
            acc[r].x = fmaf(a.z, w2.x, acc[r].x);
            acc[r].x = fmaf(a.w, w3.x, acc[r].x);
            acc[r].y = fmaf(a.x, w0.y, acc[r].y);
            acc[r].y = fmaf(a.y, w1.y, acc[r].y);
            acc[r].y = fmaf(a.z, w2.y, acc[r].y);
            acc[r].y = fmaf(a.w, w3.y, acc[r].y);
            acc[r].z = fmaf(a.x, w0.z, acc[r].z);
            acc[r].z = fmaf(a.y, w1.z, acc[r].z);
            acc[r].z = fmaf(a.z, w2.z, acc[r].z);
            acc[r].z = fmaf(a.w, w3.z, acc[r].z);
            acc[r].w = fmaf(a.x, w0.w, acc[r].w);
            acc[r].w = fmaf(a.y, w1.w, acc[r].w);
            acc[r].w = fmaf(a.z, w2.w, acc[r].w);
            acc[r].w = fmaf(a.w, w3.w, acc[r].w);
        }
    }

    #pragma unroll
    for (int r = 0; r < 8; ++r) {
        int row = row0 + tr + r;
        if (row < M) {
            if (BF16OUT) {
                ushort4 p;
                p.x = f32_to_bf16(acc[r].x);
                p.y = f32_to_bf16(acc[r].y);
                p.z = f32_to_bf16(acc[r].z);
                p.w = f32_to_bf16(acc[r].w);
                ((ushort4*)Cout)[(size_t)row * D4 + tc] = p;
            } else {
                ((float4*)Cout)[(size_t)row * D4 + tc] = acc[r];
            }
        }
    }
}

// --- Gather: out[d] += mean over edges of y16[eidx] (bf16 rows) --------
__global__ void gather_out_kernel(const unsigned short* __restrict__ y16,
                                  const int* __restrict__ offsets,
                                  const int* __restrict__ eidx,
                                  float* __restrict__ out, int N) {
    const int wave = (int)(((long long)blockIdx.x * blockDim.x + threadIdx.x) >> 6);
    const int lane = threadIdx.x & 63;
    if (wave >= N) return;
    const int h = lane >> 4;     // which edge of the quad (0..3)
    const int c = lane & 15;     // 16B chunk within the row (8 bf16)
    const int beg = offsets[wave];
    const int end = offsets[wave + 1];

    float acc[8];
    #pragma unroll
    for (int j = 0; j < 8; ++j) acc[j] = 0.f;

    for (int i = beg + h; i < end; i += 4) {
        int s = eidx[i];
        const int4 v = *reinterpret_cast<const int4*>(y16 + (size_t)s * D + c * 8);
        const unsigned short* hs = (const unsigned short*)&v;
        #pragma unroll
        for (int j = 0; j < 8; ++j) acc[j] += bf16_to_f32(hs[j]);
    }

    #pragma unroll
    for (int j = 0; j < 8; ++j) {
        acc[j] += __shfl_down(acc[j], 32);
        acc[j] += __shfl_down(acc[j], 16);
    }

    if (h == 0) {
        const float inv = 1.0f / fmaxf((float)(end - beg), 1.0f);
        float4* o = reinterpret_cast<float4*>(out + (size_t)wave * D) + c * 2;
        float4 c0 = o[0], c1 = o[1];
        c0.x = fmaf(acc[0], inv, c0.x);
        c0.y = fmaf(acc[1], inv, c0.y);
        c0.z = fmaf(acc[2], inv, c0.z);
        c0.w = fmaf(acc[3], inv, c0.w);
        c1.x = fmaf(acc[4], inv, c1.x);
        c1.y = fmaf(acc[5], inv, c1.y);
        c1.z = fmaf(acc[6], inv, c1.z);
        c1.w = fmaf(acc[7], inv, c1.w);
        o[0] = c0;
        o[1] = c1;
    }
}

extern "C" void kernel_launch(void* const* d_in, const int* in_sizes, int n_in,
                              void* d_out, int out_size, void* d_ws, size_t ws_size,
                              hipStream_t stream) {
    const float* x_src    = (const float*)d_in[0];
    const float* x_dst    = (const float*)d_in[1];
    const int*   edge_src = (const int*)d_in[2];
    const int*   edge_dst = (const int*)d_in[3];
    const float* Wn = (const float*)d_in[5];
    const float* bn = (const float*)d_in[6];
    const float* Ws = (const float*)d_in[7];
    const float* bs = (const float*)d_in[8];

    const int E     = in_sizes[2];
    const int N     = in_sizes[1] / D;   // num_dst
    const int M_SRC = in_sizes[0] / D;   // num_src

    const int NB = (N + CSIZE - 1) >> CBITS;           // coarse buckets (<=512)
    int nblk = (E + 2047) / 2048;
    if (nblk > MAXNB) nblk = MAXNB;
    const int EPB = (E + nblk - 1) / nblk;

    // ws layout: [y16: M_SRC*D ushort][packed: E][offsets: N+1][eidx: E]
    //            [Cmat: nblk*NB][ColBase: nblk*NB][colTotal: NB]
    //            [bucketBase: NB][cOff: NB+1]
    unsigned short* y16 = (unsigned short*)d_ws;
    int* packed     = (int*)(y16 + (size_t)M_SRC * D);
    int* offsets    = packed + E;
    int* eidx       = offsets + (N + 1);
    int* Cmat       = eidx + E;
    int* ColBase    = Cmat + (size_t)nblk * NB;
    int* colTotal   = ColBase + (size_t)nblk * NB;
    int* bucketBase = colTotal + NB;
    int* cOff       = bucketBase + NB;

    const int T = 256;
    count_kernel<<<nblk, T, 0, stream>>>(edge_dst, Cmat, E, NB, EPB);
    colscan_kernel<<<NB, 512, 0, stream>>>(Cmat, ColBase, colTotal, nblk, NB);
    totscan_kernel<<<1, 512, 0, stream>>>(colTotal, bucketBase, cOff, NB, E, offsets, N);
    place_kernel<<<nblk, T, 0, stream>>>(edge_src, edge_dst, bucketBase, ColBase,
                                         packed, E, NB, EPB);
    fine_kernel<<<NB, T, 0, stream>>>(packed, cOff, offsets, eidx, N);

    // y16 = bf16(x_src @ Wn)
    gemm128_kernel<true><<<(M_SRC + TM - 1) / TM, T, 0, stream>>>(
        x_src, Wn, nullptr, nullptr, y16, M_SRC);
    // out = x_dst @ Ws + bn + bs
    gemm128_kernel<false><<<(N + TM - 1) / TM, T, 0, stream>>>(
        x_dst, Ws, bn, bs, d_out, N);

    // out += mean of projected neighbor rows (bf16 rows, fp32 accum)
    gather_out_kernel<<<(N + 3) / 4, T, 0, stream>>>(
        y16, offsets, eidx, (float*)d_out, N);
}